// Round 1
// baseline (192.171 us; speedup 1.0000x reference)
//
#include <hip/hip_runtime.h>
#include <cstdint>
#include <cstddef>

typedef short s16x8 __attribute__((ext_vector_type(8)));
typedef float f32x16 __attribute__((ext_vector_type(16)));

#define WS_S     0
#define WS_ZERO  16384
#define WS_XQ    32768
#define XQ_BYTES (8 * 64 * 64 * 64 * 16)          // 33554432
#define WS_WQ    (WS_XQ + XQ_BYTES)               // 33587200
#define WQ_BYTES (4 * 32 * 9 * 2 * 128 * 8 * 2)   // 4718592
#define WS_NEEDED ((size_t)WS_WQ + (size_t)WQ_BYTES)

__device__ __forceinline__ short f2bf(float f) {
  unsigned u = __builtin_bit_cast(unsigned, f);
  unsigned r = (u + 0x7fffu + ((u >> 16) & 1u)) >> 16;  // RNE
  return (short)r;
}

__device__ __forceinline__ void gload_lds16(const void* g, void* l) {
  __builtin_amdgcn_global_load_lds(
      (const __attribute__((address_space(1))) void*)g,
      (__attribute__((address_space(3))) void*)l, 16, 0, 0);
}

// ---- s = style @ mod_w^T + mod_b ; one wave per (b,c). Also zeroes zerobuf.
__global__ void k_style(const float* __restrict__ style,
                        const float* __restrict__ mod_w,
                        const float* __restrict__ mod_b,
                        float* __restrict__ s_out,
                        float* __restrict__ zb) {
  if (blockIdx.x == 0) zb[threadIdx.x] = 0.0f;  // 256 floats = 1 KB zero page
  int wave = threadIdx.x >> 6, lane = threadIdx.x & 63;
  int wid = blockIdx.x * 4 + wave;   // 0..4095
  int b = wid >> 9, c = wid & 511;
  const float4* st = (const float4*)(style + b * 512);
  const float4* mw = (const float4*)(mod_w + c * 512);
  float4 a0 = st[lane * 2], a1 = st[lane * 2 + 1];
  float4 b0 = mw[lane * 2], b1 = mw[lane * 2 + 1];
  float sum = a0.x * b0.x + a0.y * b0.y + a0.z * b0.z + a0.w * b0.w +
              a1.x * b1.x + a1.y * b1.y + a1.z * b1.z + a1.w * b1.w;
  #pragma unroll
  for (int off = 32; off; off >>= 1) sum += __shfl_down(sum, off);
  if (lane == 0) s_out[b * 512 + c] = sum + mod_b[c];
}

// ---- xq[b][h][cgrp][w][8] = bf16(x[b][cgrp*8+j][h][w] * s[b][cgrp*8+j])
__global__ void k_xq(const float* __restrict__ x, const float* __restrict__ s,
                     char* __restrict__ xq) {
  int t = blockIdx.x * 256 + threadIdx.x;        // 2,097,152 total
  int w = t & 63, cg = (t >> 6) & 63, h = (t >> 12) & 63, b = t >> 18;
  const float* xp = x + (((b * 512 + cg * 8) * 64 + h) * 64 + w);
  const float* sp = s + b * 512 + cg * 8;
  s16x8 v;
  #pragma unroll
  for (int j = 0; j < 8; ++j) v[j] = f2bf(xp[j * 4096] * sp[j]);
  *(s16x8*)(xq + (size_t)t * 16) = v;
}

// ---- wq[nb][chunk][tap][kg][n][8k] = bf16(weight[nb*128+n][chunk*16+kg*8+k][tap])
__global__ void k_wq(const float* __restrict__ wt, char* __restrict__ wq) {
  int tap = blockIdx.x, ch = blockIdx.y, nb = blockIdx.z;
  int kg = threadIdx.x >> 7, n = threadIdx.x & 127;
  const float* wp = wt + ((size_t)(nb * 128 + n) * 512 + ch * 16 + kg * 8) * 9 + tap;
  s16x8 v;
  #pragma unroll
  for (int j = 0; j < 8; ++j) v[j] = f2bf(wp[j * 9]);
  size_t idx = ((size_t)(nb * 32 + ch) * 9 + tap) * 256 + kg * 128 + n;  // 16B units
  *(s16x8*)(wq + idx * 16) = v;
}

// ---- conv: block = 128 couts (nb) x 128 pixels (mb = 2 rows of one image)
__global__ __launch_bounds__(256, 3) void k_conv(
    const char* __restrict__ xq, const char* __restrict__ wq,
    const char* __restrict__ zerob, float* __restrict__ out) {
  __shared__ short wt_lds[18432];   // [9 tap][2 kg][128 n][8 k]   = 36864 B
  __shared__ short xs_lds[4224];    // [4 row][2 kg][66 col][8 k]  = 8448 B
  const int tid = threadIdx.x;
  const int lane = tid & 63, wave = tid >> 6;
  const int l5 = lane >> 5, l31 = lane & 31;
  const int mb = blockIdx.x, nb = blockIdx.y;
  const int wave_c = wave >> 1, wave_p = wave & 1;
  const int b = mb >> 5;               // 32 m-blocks per image
  const int row0 = (mb << 1) & 63;     // first of the 2 output rows

  // zero the halo columns (col 0 and 65 of each [row][kg] plane), written once
  if (tid < 16) {
    int rk = tid >> 1, col = (tid & 1) * 65;
    s16x8 z = {0, 0, 0, 0, 0, 0, 0, 0};
    *(s16x8*)&xs_lds[(rk * 66 + col) * 8] = z;
  }

  f32x16 acc[2][2];
  #pragma unroll
  for (int i = 0; i < 2; ++i)
    #pragma unroll
    for (int j = 0; j < 2; ++j)
      #pragma unroll
      for (int e = 0; e < 16; ++e) acc[i][j][e] = 0.0f;

  const char* wq_b = wq + (size_t)nb * 32 * 36864 + (size_t)(wave * 9) * 1024 + lane * 16;
  const char* xq_b = xq + (size_t)b * 4194304 + lane * 16;
  char* wt_dst = (char*)wt_lds + wave * 9 * 1024;

  for (int ch = 0; ch < 32; ++ch) {
    __syncthreads();  // previous compute done before overwriting LDS
    // stage weights for this 16-channel chunk: 36864 B, 9 x 1KB per wave
    const char* wsrc = wq_b + (size_t)ch * 36864;
    #pragma unroll
    for (int i = 0; i < 9; ++i)
      gload_lds16(wsrc + i * 1024, wt_dst + i * 1024);
    // stage x rows row0-1 .. row0+2 (2 kgroups each): 8 x 1KB, 2 per wave
    #pragma unroll
    for (int jj = 0; jj < 2; ++jj) {
      int j = wave * 2 + jj;
      int r = j >> 1, kg = j & 1;
      int row = row0 - 1 + r;
      const char* src = (row >= 0 && row < 64)
          ? xq_b + (size_t)row * 65536 + (size_t)(ch * 2 + kg) * 1024
          : zerob + lane * 16;
      gload_lds16(src, (char*)xs_lds + (size_t)((r * 2 + kg) * 66 + 1) * 16);
    }
    asm volatile("s_waitcnt vmcnt(0)" ::: "memory");
    __syncthreads();

    // compute: 9 taps x (2 cout-tiles x 2 pixel-tiles) MFMAs
    #pragma unroll
    for (int kh = 0; kh < 3; ++kh) {
      #pragma unroll
      for (int kw = 0; kw < 3; ++kw) {
        const int tap = kh * 3 + kw;
        s16x8 afr[2], bfr[2];
        #pragma unroll
        for (int ct = 0; ct < 2; ++ct) {
          int n = wave_c * 64 + ct * 32 + l31;
          afr[ct] = *(const s16x8*)&wt_lds[((tap * 2 + l5) * 128 + n) * 8];
        }
        #pragma unroll
        for (int pt = 0; pt < 2; ++pt) {
          int pxl = wave_p * 64 + pt * 32 + l31;
          int r = (pxl >> 6) + kh;
          int col = (pxl & 63) + kw;
          bfr[pt] = *(const s16x8*)&xs_lds[((r * 2 + l5) * 66 + col) * 8];
        }
        #pragma unroll
        for (int ct = 0; ct < 2; ++ct)
          #pragma unroll
          for (int pt = 0; pt < 2; ++pt)
            acc[ct][pt] = __builtin_amdgcn_mfma_f32_32x32x16_bf16(
                afr[ct], bfr[pt], acc[ct][pt], 0, 0, 0);
      }
    }
  }

  // epilogue: D row = cout, col = pixel (lanes 0..31 contiguous w -> coalesced)
  #pragma unroll
  for (int ct = 0; ct < 2; ++ct) {
    #pragma unroll
    for (int pt = 0; pt < 2; ++pt) {
      int pxl = wave_p * 64 + pt * 32 + l31;
      int h = row0 + (pxl >> 6);
      int w = pxl & 63;
      int cb = nb * 128 + wave_c * 64 + ct * 32 + 4 * l5;
      #pragma unroll
      for (int rg = 0; rg < 16; ++rg) {
        int cout = cb + (rg & 3) + 8 * (rg >> 2);
        out[((size_t)(b * 512 + cout) * 4096) + h * 64 + w] = acc[ct][pt][rg];
      }
    }
  }
}

// ---- emergency fallback (tiny ws): fp32 direct conv, s recomputed per block
__global__ void k_naive(const float* __restrict__ x, const float* __restrict__ style,
                        const float* __restrict__ wt, const float* __restrict__ mw,
                        const float* __restrict__ mb_, float* __restrict__ out) {
  __shared__ float s_sh[512];
  int h = blockIdx.x, co = blockIdx.y, b = blockIdx.z, w = threadIdx.x;
  for (int c = w; c < 512; c += 64) {
    float a = mb_[c];
    for (int k = 0; k < 512; ++k) a += style[b * 512 + k] * mw[c * 512 + k];
    s_sh[c] = a;
  }
  __syncthreads();
  float acc = 0.0f;
  for (int c = 0; c < 512; ++c) {
    float sc = s_sh[c];
    const float* wp = wt + ((size_t)co * 512 + c) * 9;
    for (int kh = 0; kh < 3; ++kh) {
      int hy = h + kh - 1;
      if (hy < 0 || hy >= 64) continue;
      for (int kw = 0; kw < 3; ++kw) {
        int wx = w + kw - 1;
        if (wx < 0 || wx >= 64) continue;
        acc += wp[kh * 3 + kw] * x[((size_t)(b * 512 + c) * 64 + hy) * 64 + wx] * sc;
      }
    }
  }
  out[((size_t)(b * 512 + co) * 64 + h) * 64 + w] = acc;
}

extern "C" void kernel_launch(void* const* d_in, const int* in_sizes, int n_in,
                              void* d_out, int out_size, void* d_ws, size_t ws_size,
                              hipStream_t stream) {
  const float* x      = (const float*)d_in[0];
  const float* style  = (const float*)d_in[1];
  const float* weight = (const float*)d_in[2];
  const float* mod_w  = (const float*)d_in[3];
  const float* mod_b  = (const float*)d_in[4];
  float* out = (float*)d_out;
  char* ws = (char*)d_ws;

  if (ws_size >= WS_NEEDED) {
    float* s  = (float*)(ws + WS_S);
    float* zb = (float*)(ws + WS_ZERO);
    char* xq  = ws + WS_XQ;
    char* wq  = ws + WS_WQ;
    k_style<<<1024, 256, 0, stream>>>(style, mod_w, mod_b, s, zb);
    k_xq<<<8192, 256, 0, stream>>>(x, s, xq);
    k_wq<<<dim3(9, 32, 4), 256, 0, stream>>>(weight, wq);
    k_conv<<<dim3(256, 4), 256, 0, stream>>>(xq, wq, (const char*)zb, out);
  } else {
    k_naive<<<dim3(64, 512, 8), 64, 0, stream>>>(x, style, weight, mod_w, mod_b, out);
  }
}

// Round 2
// 157.389 us; speedup vs baseline: 1.2210x; 1.2210x over previous
//
#include <hip/hip_runtime.h>
#include <cstdint>
#include <cstddef>

typedef short s16x8 __attribute__((ext_vector_type(8)));
typedef float f32x16 __attribute__((ext_vector_type(16)));

#define WS_S     0
#define WS_ZERO  16384
#define WS_XQ    32768
#define XQ_BYTES (8 * 64 * 64 * 64 * 16)          // 33554432
#define WS_WQ    (WS_XQ + XQ_BYTES)               // 33587200
#define WQ_BYTES (4 * 32 * 9 * 2 * 128 * 8 * 2)   // 4718592
#define WS_NEEDED ((size_t)WS_WQ + (size_t)WQ_BYTES)

__device__ __forceinline__ short f2bf(float f) {
  unsigned u = __builtin_bit_cast(unsigned, f);
  unsigned r = (u + 0x7fffu + ((u >> 16) & 1u)) >> 16;  // RNE
  return (short)r;
}

__device__ __forceinline__ void gload_lds16(const void* g, void* l) {
  __builtin_amdgcn_global_load_lds(
      (const __attribute__((address_space(1))) void*)g,
      (__attribute__((address_space(3))) void*)l, 16, 0, 0);
}

// ---- s = style @ mod_w^T + mod_b ; one wave per (b,c). Also zeroes zerobuf.
__global__ void k_style(const float* __restrict__ style,
                        const float* __restrict__ mod_w,
                        const float* __restrict__ mod_b,
                        float* __restrict__ s_out,
                        float* __restrict__ zb) {
  if (blockIdx.x == 0) zb[threadIdx.x] = 0.0f;  // 256 floats = 1 KB zero page
  int wave = threadIdx.x >> 6, lane = threadIdx.x & 63;
  int wid = blockIdx.x * 4 + wave;   // 0..4095
  int b = wid >> 9, c = wid & 511;
  const float4* st = (const float4*)(style + b * 512);
  const float4* mw = (const float4*)(mod_w + c * 512);
  float4 a0 = st[lane * 2], a1 = st[lane * 2 + 1];
  float4 b0 = mw[lane * 2], b1 = mw[lane * 2 + 1];
  float sum = a0.x * b0.x + a0.y * b0.y + a0.z * b0.z + a0.w * b0.w +
              a1.x * b1.x + a1.y * b1.y + a1.z * b1.z + a1.w * b1.w;
  #pragma unroll
  for (int off = 32; off; off >>= 1) sum += __shfl_down(sum, off);
  if (lane == 0) s_out[b * 512 + c] = sum + mod_b[c];
}

// ---- xq[b][h][cgrp][w][8] = bf16(x[b][cgrp*8+j][h][w] * s[b][cgrp*8+j])
__global__ void k_xq(const float* __restrict__ x, const float* __restrict__ s,
                     char* __restrict__ xq) {
  int t = blockIdx.x * 256 + threadIdx.x;        // 2,097,152 total
  int w = t & 63, cg = (t >> 6) & 63, h = (t >> 12) & 63, b = t >> 18;
  const float* xp = x + (((b * 512 + cg * 8) * 64 + h) * 64 + w);
  const float* sp = s + b * 512 + cg * 8;
  s16x8 v;
  #pragma unroll
  for (int j = 0; j < 8; ++j) v[j] = f2bf(xp[j * 4096] * sp[j]);
  *(s16x8*)(xq + (size_t)t * 16) = v;
}

// ---- wq[nb][chunk][tap][kg][n][8k] = bf16(weight[nb*128+n][chunk*16+kg*8+k][tap])
__global__ void k_wq(const float* __restrict__ wt, char* __restrict__ wq) {
  int tap = blockIdx.x, ch = blockIdx.y, nb = blockIdx.z;
  int kg = threadIdx.x >> 7, n = threadIdx.x & 127;
  const float* wp = wt + ((size_t)(nb * 128 + n) * 512 + ch * 16 + kg * 8) * 9 + tap;
  s16x8 v;
  #pragma unroll
  for (int j = 0; j < 8; ++j) v[j] = f2bf(wp[j * 9]);
  size_t idx = ((size_t)(nb * 32 + ch) * 9 + tap) * 256 + kg * 128 + n;  // 16B units
  *(s16x8*)(wq + idx * 16) = v;
}

// ---- conv: block = 128 couts (nb) x 512 pixels (8 rows of one image)
// 4 waves, each computes the FULL 128x128 wave tile (128 couts x 2 rows).
// LDS double-buffered; 2-phase prefetch (issue next chunk's global_load_lds
// before computing current chunk; the single __syncthreads per chunk drains).
__global__ __launch_bounds__(256, 1) void k_conv(
    const char* __restrict__ xq, const char* __restrict__ wq,
    const char* __restrict__ zerob, float* __restrict__ out) {
  extern __shared__ char smem[];
  // layout: wt[2][36864] then xs[2][21120]   total 115968 B
  char* wt_base = smem;
  char* xs_base = smem + 73728;

  const int tid = threadIdx.x;
  const int lane = tid & 63, wave = tid >> 6;     // wave = pixel-slice wp
  const int l5 = lane >> 5, l31 = lane & 31;
  const int mb = blockIdx.x, nb = blockIdx.y;
  const int b = mb >> 3;                 // 8 m-blocks (of 8 rows) per image
  const int row0 = (mb & 7) << 3;        // first of the 8 output rows

  // zero halo columns (col 0 and 65 of each [row j][kg] plane) in BOTH buffers
  if (tid < 80) {
    int dbuf = tid / 40, q = tid % 40;
    int j = q >> 2, kg = (q >> 1) & 1, side = q & 1;
    s16x8 z = {0, 0, 0, 0, 0, 0, 0, 0};
    *(s16x8*)(xs_base + dbuf * 21120 + ((j * 2 + kg) * 66 + side * 65) * 16) = z;
  }

  f32x16 acc[4][4];
  #pragma unroll
  for (int i = 0; i < 4; ++i)
    #pragma unroll
    for (int j = 0; j < 4; ++j)
      #pragma unroll
      for (int e = 0; e < 16; ++e) acc[i][j][e] = 0.0f;

  // staging source bases (per-lane), dst bases (wave-uniform)
  const char* wq_base = wq + (size_t)nb * (32 * 36864) + wave * 9216 + lane * 16;
  const char* xq_base = xq + (size_t)b * 4194304 + lane * 16;

  const int a_off = l5 * 2048 + l31 * 16;       // within wt chunk
  const int b_off = l5 * 1056 + l31 * 16;       // within xs chunk
  const int xs_woff = wave * 4224;              // wave's 2-row pixel slice

  // ---- stage chunk `ch` into buffer `buf` (14 gload_lds per wave)
  #define STAGE(buf, ch)                                                      \
    {                                                                         \
      const char* wsrc = wq_base + (size_t)(ch) * 36864;                      \
      char* wdst = wt_base + (buf) * 36864 + wave * 9216;                     \
      _Pragma("unroll")                                                       \
      for (int i = 0; i < 9; ++i)                                             \
        gload_lds16(wsrc + i * 1024, wdst + i * 1024);                        \
      _Pragma("unroll")                                                       \
      for (int i = 0; i < 5; ++i) {                                           \
        int seg = wave * 5 + i;            /* 0..19 */                        \
        int j = seg >> 1, kg = seg & 1;                                       \
        int h = row0 - 1 + j;                                                 \
        const char* src = (h >= 0 && h < 64)                                  \
            ? xq_base + (size_t)((h * 64 + (ch) * 2 + kg)) * 1024             \
            : zerob + lane * 16;                                              \
        gload_lds16(src, xs_base + (buf) * 21120 + ((j * 2 + kg) * 66 + 1) * 16); \
      }                                                                       \
    }

  STAGE(0, 0);
  __syncthreads();   // drains vmcnt + the halo ds_writes

  for (int ch = 0; ch < 32; ++ch) {
    const int cur = ch & 1;
    if (ch < 31) STAGE(cur ^ 1, ch + 1);

    const char* wt = wt_base + cur * 36864;
    const char* xs_w = xs_base + cur * 21120 + xs_woff;

    #pragma unroll
    for (int kw = 0; kw < 3; ++kw) {
      // B-fragment cache: 4 input rows x 2 col-halves, reused across kh
      s16x8 bC[4][2];
      #pragma unroll
      for (int r4 = 0; r4 < 4; ++r4)
        #pragma unroll
        for (int chh = 0; chh < 2; ++chh)
          bC[r4][chh] = *(const s16x8*)(xs_w + (r4 * 132 + chh * 32 + kw) * 16 + b_off);
      #pragma unroll
      for (int kh = 0; kh < 3; ++kh) {
        const int tap = kh * 3 + kw;
        s16x8 afr[4];
        #pragma unroll
        for (int ct = 0; ct < 4; ++ct)
          afr[ct] = *(const s16x8*)(wt + tap * 4096 + ct * 512 + a_off);
        #pragma unroll
        for (int ct = 0; ct < 4; ++ct)
          #pragma unroll
          for (int pt = 0; pt < 4; ++pt)
            acc[ct][pt] = __builtin_amdgcn_mfma_f32_32x32x16_bf16(
                afr[ct], bC[(pt >> 1) + kh][pt & 1], acc[ct][pt], 0, 0, 0);
      }
    }
    __syncthreads();   // implicit vmcnt(0): next buffer staged; reads of cur done
  }

  // epilogue: D row = cout, col = pixel (lanes 0..31 contiguous w -> coalesced)
  #pragma unroll
  for (int ct = 0; ct < 4; ++ct) {
    #pragma unroll
    for (int pt = 0; pt < 4; ++pt) {
      int h = row0 + wave * 2 + (pt >> 1);
      int w = (pt & 1) * 32 + l31;
      int cb = nb * 128 + ct * 32 + 4 * l5;
      #pragma unroll
      for (int rg = 0; rg < 16; ++rg) {
        int cout = cb + (rg & 3) + 8 * (rg >> 2);
        out[((size_t)(b * 512 + cout) * 4096) + h * 64 + w] = acc[ct][pt][rg];
      }
    }
  }
  #undef STAGE
}

// ---- emergency fallback (tiny ws): fp32 direct conv, s recomputed per block
__global__ void k_naive(const float* __restrict__ x, const float* __restrict__ style,
                        const float* __restrict__ wt, const float* __restrict__ mw,
                        const float* __restrict__ mb_, float* __restrict__ out) {
  __shared__ float s_sh[512];
  int h = blockIdx.x, co = blockIdx.y, b = blockIdx.z, w = threadIdx.x;
  for (int c = w; c < 512; c += 64) {
    float a = mb_[c];
    for (int k = 0; k < 512; ++k) a += style[b * 512 + k] * mw[c * 512 + k];
    s_sh[c] = a;
  }
  __syncthreads();
  float acc = 0.0f;
  for (int c = 0; c < 512; ++c) {
    float sc = s_sh[c];
    const float* wp = wt + ((size_t)co * 512 + c) * 9;
    for (int kh = 0; kh < 3; ++kh) {
      int hy = h + kh - 1;
      if (hy < 0 || hy >= 64) continue;
      for (int kw = 0; kw < 3; ++kw) {
        int wx = w + kw - 1;
        if (wx < 0 || wx >= 64) continue;
        acc += wp[kh * 3 + kw] * x[((size_t)(b * 512 + c) * 64 + hy) * 64 + wx] * sc;
      }
    }
  }
  out[((size_t)(b * 512 + co) * 64 + h) * 64 + w] = acc;
}

extern "C" void kernel_launch(void* const* d_in, const int* in_sizes, int n_in,
                              void* d_out, int out_size, void* d_ws, size_t ws_size,
                              hipStream_t stream) {
  const float* x      = (const float*)d_in[0];
  const float* style  = (const float*)d_in[1];
  const float* weight = (const float*)d_in[2];
  const float* mod_w  = (const float*)d_in[3];
  const float* mod_b  = (const float*)d_in[4];
  float* out = (float*)d_out;
  char* ws = (char*)d_ws;

  if (ws_size >= WS_NEEDED) {
    float* s  = (float*)(ws + WS_S);
    float* zb = (float*)(ws + WS_ZERO);
    char* xq  = ws + WS_XQ;
    char* wq  = ws + WS_WQ;
    k_style<<<1024, 256, 0, stream>>>(style, mod_w, mod_b, s, zb);
    k_xq<<<8192, 256, 0, stream>>>(x, s, xq);
    k_wq<<<dim3(9, 32, 4), 256, 0, stream>>>(weight, wq);
    k_conv<<<dim3(64, 4), 256, 115968, stream>>>(xq, wq, (const char*)zb, out);
  } else {
    k_naive<<<dim3(64, 512, 8), 64, 0, stream>>>(x, style, weight, mod_w, mod_b, out);
  }
}

// Round 3
// 154.023 us; speedup vs baseline: 1.2477x; 1.0218x over previous
//
#include <hip/hip_runtime.h>
#include <cstdint>
#include <cstddef>

typedef short s16x8 __attribute__((ext_vector_type(8)));
typedef float f32x16 __attribute__((ext_vector_type(16)));

#define WS_S     0
#define WS_ZERO  16384
#define WS_XQ    32768
#define XQ_BYTES (8 * 64 * 64 * 64 * 16)          // 33554432
#define WS_WQ    (WS_XQ + XQ_BYTES)               // 33587200
#define WQ_BYTES (4 * 32 * 9 * 2 * 128 * 8 * 2)   // 4718592
#define WS_NEEDED ((size_t)WS_WQ + (size_t)WQ_BYTES)

__device__ __forceinline__ short f2bf(float f) {
  unsigned u = __builtin_bit_cast(unsigned, f);
  unsigned r = (u + 0x7fffu + ((u >> 16) & 1u)) >> 16;  // RNE
  return (short)r;
}

__device__ __forceinline__ void gload_lds16(const void* g, void* l) {
  __builtin_amdgcn_global_load_lds(
      (const __attribute__((address_space(1))) void*)g,
      (__attribute__((address_space(3))) void*)l, 16, 0, 0);
}

// ---- s = style @ mod_w^T + mod_b ; one wave per (b,c). Also zeroes zerobuf.
__global__ void k_style(const float* __restrict__ style,
                        const float* __restrict__ mod_w,
                        const float* __restrict__ mod_b,
                        float* __restrict__ s_out,
                        float* __restrict__ zb) {
  if (blockIdx.x == 0) zb[threadIdx.x] = 0.0f;  // 256 floats = 1 KB zero page
  int wave = threadIdx.x >> 6, lane = threadIdx.x & 63;
  int wid = blockIdx.x * 4 + wave;   // 0..4095
  int b = wid >> 9, c = wid & 511;
  const float4* st = (const float4*)(style + b * 512);
  const float4* mw = (const float4*)(mod_w + c * 512);
  float4 a0 = st[lane * 2], a1 = st[lane * 2 + 1];
  float4 b0 = mw[lane * 2], b1 = mw[lane * 2 + 1];
  float sum = a0.x * b0.x + a0.y * b0.y + a0.z * b0.z + a0.w * b0.w +
              a1.x * b1.x + a1.y * b1.y + a1.z * b1.z + a1.w * b1.w;
  #pragma unroll
  for (int off = 32; off; off >>= 1) sum += __shfl_down(sum, off);
  if (lane == 0) s_out[b * 512 + c] = sum + mod_b[c];
}

// ---- xq[b][h][cgrp][w][8] = bf16(x[b][cgrp*8+j][h][w] * s[b][cgrp*8+j])
__global__ void k_xq(const float* __restrict__ x, const float* __restrict__ s,
                     char* __restrict__ xq) {
  int t = blockIdx.x * 256 + threadIdx.x;        // 2,097,152 total
  int w = t & 63, cg = (t >> 6) & 63, h = (t >> 12) & 63, b = t >> 18;
  const float* xp = x + (((b * 512 + cg * 8) * 64 + h) * 64 + w);
  const float* sp = s + b * 512 + cg * 8;
  s16x8 v;
  #pragma unroll
  for (int j = 0; j < 8; ++j) v[j] = f2bf(xp[j * 4096] * sp[j]);
  *(s16x8*)(xq + (size_t)t * 16) = v;
}

// ---- wq[nb][chunk][tap][kg][n][8k] = bf16(weight[nb*128+n][chunk*16+kg*8+k][tap])
__global__ void k_wq(const float* __restrict__ wt, char* __restrict__ wq) {
  int tap = blockIdx.x, ch = blockIdx.y, nb = blockIdx.z;
  int kg = threadIdx.x >> 7, n = threadIdx.x & 127;
  const float* wp = wt + ((size_t)(nb * 128 + n) * 512 + ch * 16 + kg * 8) * 9 + tap;
  s16x8 v;
  #pragma unroll
  for (int j = 0; j < 8; ++j) v[j] = f2bf(wp[j * 9]);
  size_t idx = ((size_t)(nb * 32 + ch) * 9 + tap) * 256 + kg * 128 + n;  // 16B units
  *(s16x8*)(wq + idx * 16) = v;
}

// ---- conv: block = 128 couts (nb) x 512 pixels (8 rows of one image)
// 8 waves (2 cout-halves x 4 pixel-slices), wave tile 64 couts x 128 px.
// acc = 2x4 f32x16 = 128 regs -> 2 waves/SIMD for latency hiding.
// LDS double-buffered; 2-phase prefetch, 1 barrier per chunk.
__global__ __launch_bounds__(512, 2) void k_conv(
    const char* __restrict__ xq, const char* __restrict__ wq,
    const char* __restrict__ zerob, float* __restrict__ out) {
  extern __shared__ char smem[];
  // layout: wt[2][36864] then xs[2][21120]   total 115968 B
  char* wt_base = smem;
  char* xs_base = smem + 73728;

  const int tid = threadIdx.x;
  const int lane = tid & 63, wave = tid >> 6;
  const int l5 = lane >> 5, l31 = lane & 31;
  const int wc = wave >> 2;            // cout half (0,1)
  const int wp = wave & 3;             // pixel slice (2 rows each)
  const int mb = blockIdx.x, nb = blockIdx.y;
  const int b = mb >> 3;               // 8 m-blocks (of 8 rows) per image
  const int row0 = (mb & 7) << 3;      // first of the 8 output rows

  // zero halo columns (col 0 and 65 of each [row j][kg] plane) in BOTH buffers
  if (tid < 80) {
    int dbuf = tid / 40, q = tid % 40;
    int j = q >> 2, kg = (q >> 1) & 1, side = q & 1;
    s16x8 z = {0, 0, 0, 0, 0, 0, 0, 0};
    *(s16x8*)(xs_base + dbuf * 21120 + ((j * 2 + kg) * 66 + side * 65) * 16) = z;
  }

  f32x16 acc[2][4];
  #pragma unroll
  for (int i = 0; i < 2; ++i)
    #pragma unroll
    for (int j = 0; j < 4; ++j)
      #pragma unroll
      for (int e = 0; e < 16; ++e) acc[i][j][e] = 0.0f;

  // staging source bases (per-lane), dst bases (wave-uniform via seg)
  const char* wq_base = wq + (size_t)nb * (32 * 36864) + lane * 16;
  const char* xq_base = xq + (size_t)b * 4194304 + lane * 16;

  const int a_off = l5 * 2048 + l31 * 16;       // within wt chunk (kg, n)
  const int b_off = l5 * 1056 + l31 * 16;       // within xs chunk (kg, col)
  const int xs_woff = wp * 4224;                // wave's 2-row pixel slice

  // ---- stage chunk `ch` into buffer `buf`: 56 x 1KB segs, 7 per wave
  #define STAGE(buf, ch)                                                      \
    _Pragma("unroll")                                                         \
    for (int i = 0; i < 7; ++i) {                                             \
      int seg = wave * 7 + i;             /* 0..55, wave-uniform */           \
      if (seg < 36) {                                                         \
        gload_lds16(wq_base + (size_t)(ch) * 36864 + seg * 1024,              \
                    wt_base + (buf) * 36864 + seg * 1024);                    \
      } else {                                                                \
        int q = seg - 36, j = q >> 1, kg = q & 1;                             \
        int h = row0 - 1 + j;                                                 \
        const char* src = (h >= 0 && h < 64)                                  \
            ? xq_base + (size_t)(h * 64 + (ch) * 2 + kg) * 1024               \
            : zerob + lane * 16;                                              \
        gload_lds16(src, xs_base + (buf) * 21120 + ((j * 2 + kg) * 66 + 1) * 16); \
      }                                                                       \
    }

  STAGE(0, 0);
  __syncthreads();   // drains vmcnt + the halo ds_writes

  for (int ch = 0; ch < 32; ++ch) {
    const int cur = ch & 1;
    if (ch < 31) STAGE(cur ^ 1, ch + 1);

    const char* wt = wt_base + cur * 36864;
    const char* xs_w = xs_base + cur * 21120 + xs_woff;

    #pragma unroll
    for (int kw = 0; kw < 3; ++kw) {
      // B-fragment cache: 4 input rows x 2 col-halves, reused across kh
      s16x8 bC[4][2];
      #pragma unroll
      for (int r4 = 0; r4 < 4; ++r4)
        #pragma unroll
        for (int chh = 0; chh < 2; ++chh)
          bC[r4][chh] = *(const s16x8*)(xs_w + (r4 * 132 + chh * 32 + kw) * 16 + b_off);
      #pragma unroll
      for (int kh = 0; kh < 3; ++kh) {
        const int tap = kh * 3 + kw;
        s16x8 afr[2];
        #pragma unroll
        for (int ct = 0; ct < 2; ++ct)
          afr[ct] = *(const s16x8*)(wt + tap * 4096 + (wc * 2 + ct) * 512 + a_off);
        #pragma unroll
        for (int ct = 0; ct < 2; ++ct)
          #pragma unroll
          for (int pt = 0; pt < 4; ++pt)
            acc[ct][pt] = __builtin_amdgcn_mfma_f32_32x32x16_bf16(
                afr[ct], bC[(pt >> 1) + kh][pt & 1], acc[ct][pt], 0, 0, 0);
      }
    }
    __syncthreads();   // implicit vmcnt(0): next buffer staged; reads of cur done
  }

  // epilogue: D row = cout, col = pixel (lanes 0..31 contiguous w -> coalesced)
  #pragma unroll
  for (int ct = 0; ct < 2; ++ct) {
    #pragma unroll
    for (int pt = 0; pt < 4; ++pt) {
      int h = row0 + wp * 2 + (pt >> 1);
      int w = (pt & 1) * 32 + l31;
      int cb = nb * 128 + wc * 64 + ct * 32 + 4 * l5;
      #pragma unroll
      for (int rg = 0; rg < 16; ++rg) {
        int cout = cb + (rg & 3) + 8 * (rg >> 2);
        out[((size_t)(b * 512 + cout) * 4096) + h * 64 + w] = acc[ct][pt][rg];
      }
    }
  }
  #undef STAGE
}

// ---- emergency fallback (tiny ws): fp32 direct conv, s recomputed per block
__global__ void k_naive(const float* __restrict__ x, const float* __restrict__ style,
                        const float* __restrict__ wt, const float* __restrict__ mw,
                        const float* __restrict__ mb_, float* __restrict__ out) {
  __shared__ float s_sh[512];
  int h = blockIdx.x, co = blockIdx.y, b = blockIdx.z, w = threadIdx.x;
  for (int c = w; c < 512; c += 64) {
    float a = mb_[c];
    for (int k = 0; k < 512; ++k) a += style[b * 512 + k] * mw[c * 512 + k];
    s_sh[c] = a;
  }
  __syncthreads();
  float acc = 0.0f;
  for (int c = 0; c < 512; ++c) {
    float sc = s_sh[c];
    const float* wp = wt + ((size_t)co * 512 + c) * 9;
    for (int kh = 0; kh < 3; ++kh) {
      int hy = h + kh - 1;
      if (hy < 0 || hy >= 64) continue;
      for (int kw = 0; kw < 3; ++kw) {
        int wx = w + kw - 1;
        if (wx < 0 || wx >= 64) continue;
        acc += wp[kh * 3 + kw] * x[((size_t)(b * 512 + c) * 64 + hy) * 64 + wx] * sc;
      }
    }
  }
  out[((size_t)(b * 512 + co) * 64 + h) * 64 + w] = acc;
}

extern "C" void kernel_launch(void* const* d_in, const int* in_sizes, int n_in,
                              void* d_out, int out_size, void* d_ws, size_t ws_size,
                              hipStream_t stream) {
  const float* x      = (const float*)d_in[0];
  const float* style  = (const float*)d_in[1];
  const float* weight = (const float*)d_in[2];
  const float* mod_w  = (const float*)d_in[3];
  const float* mod_b  = (const float*)d_in[4];
  float* out = (float*)d_out;
  char* ws = (char*)d_ws;

  if (ws_size >= WS_NEEDED) {
    float* s  = (float*)(ws + WS_S);
    float* zb = (float*)(ws + WS_ZERO);
    char* xq  = ws + WS_XQ;
    char* wq  = ws + WS_WQ;
    k_style<<<1024, 256, 0, stream>>>(style, mod_w, mod_b, s, zb);
    k_xq<<<8192, 256, 0, stream>>>(x, s, xq);
    k_wq<<<dim3(9, 32, 4), 256, 0, stream>>>(weight, wq);
    k_conv<<<dim3(64, 4), 512, 115968, stream>>>(xq, wq, (const char*)zb, out);
  } else {
    k_naive<<<dim3(64, 512, 8), 64, 0, stream>>>(x, style, weight, mod_w, mod_b, out);
  }
}